// Round 7
// baseline (420.243 us; speedup 1.0000x reference)
//
#include <hip/hip_runtime.h>
#include <stdint.h>

// CDSSM: conv1(128ch,k3) -> tanh -> conv2(128ch,k3) -> tanh -> max_t -> proj -> tanh
//        then dots(q·pos, q·negs) -> gamma -> softmax.  B=64,T=2048,D=K=K2=128,L=64,J=2.
// R7: fat-wave amortization. R4-proven register config (plain launch_bounds(512),
//     2 waves/SIMD). Each wave now owns 4 col-tiles (acc=64 AGPR): window 256 cols,
//     NIT 9->5, barriers ~halved, A-traffic/output halved. L2 epilogue keeps the
//     running max PRE-tanh (tanh monotone, bias per-row) -> bias+tanh moved to k2.
//     Staging split into 3 rounds (va[6]) interleaved with L2's three f-phases.

typedef __bf16 bf16x8 __attribute__((ext_vector_type(8)));
typedef __bf16 bf16x4 __attribute__((ext_vector_type(4)));
typedef float f32x16 __attribute__((ext_vector_type(16)));
typedef unsigned short u16x8 __attribute__((ext_vector_type(8)));

__device__ __forceinline__ unsigned short f2bf(float f) {
  unsigned u = __builtin_bit_cast(unsigned, f);
  u = u + 0x7FFFu + ((u >> 16) & 1u);   // RTNE
  return (unsigned short)(u >> 16);
}

__device__ __forceinline__ float fast_tanh(float x) {
  x = fminf(10.0f, fmaxf(-10.0f, x));
  float t = __builtin_amdgcn_exp2f(x * -2.8853900817779268f);   // e^{-2x}
  return (1.0f - t) * __builtin_amdgcn_rcpf(1.0f + t);
}

// ---------------- prep: fp32 [k][d][f] -> bf16 fragment-major [br][f][kk][row][hi][j] ----------------
__global__ void prep_kernel(const float* __restrict__ qw1, const float* __restrict__ qw2,
                            const float* __restrict__ dw1, const float* __restrict__ dw2,
                            unsigned short* __restrict__ W1f, unsigned short* __restrict__ W2f) {
  int gid = blockIdx.x * 256 + threadIdx.x;          // 768*256 = 196608 exact
  int which = gid >= 98304;                          // 0: W1f, 1: W2f
  int e = which ? gid - 98304 : gid;
  int br = e / 49152; int r = e % 49152;
  int f = r / 16384; int r2 = r & 16383;
  int kk = r2 >> 11; int row = (r2 >> 4) & 127; int hi = (r2 >> 3) & 1; int j = r2 & 7;
  int c = kk * 16 + hi * 8 + j;
  const float* src = which ? (br ? dw2 : qw2) : (br ? dw1 : qw1);
  (which ? W2f : W1f)[e] = f2bf(src[row * 384 + c * 3 + f]);
}

// ---------------- main fused conv kernel ----------------
// LDS (dynamic, 132096 B, 1 block/CU):
//  XS  0      : bf16 [258 slot][128 d], swizzled   (66048)
//  H1S 66048  : bf16 [256 slot][128 k], swizzled   (65536)
//  B1  131584 : float[128] bias1                   (512)
#define XS_OFF  0
#define H1S_OFF 66048
#define B1_OFF  131584
#define LDS_TOTAL 132096
#define WIN 258        // X slots per window
#define STRIDE 254     // fresh outputs per iter (256 h1 cols - 2)
#define NIT 5          // ceil(1022/254)
#define NCHUNK (WIN*16)   // 4128 16B-LDS chunks per window

// staging round r (0..2): issue loads into va, later convert+write. c2 in [r*1536, r*1536+1536)
#define STAGE_ISSUE(R)                                                          \
  {                                                                             \
    _Pragma("unroll")                                                           \
    for (int u = 0; u < 3; ++u) {                                               \
      int c2 = tid + (R) * 1536 + u * 512;                                      \
      if (c2 < NCHUNK) {                                                        \
        int slot = c2 >> 4;                                                     \
        int d0 = (c2 & 15) * 8;                                                 \
        int t = basen + slot; if (t > 2047) t = 2047;                           \
        const float* src = xptr + ((size_t)t * 128 + d0);                       \
        va[2 * u]     = *(const float4*)src;                                    \
        va[2 * u + 1] = *(const float4*)(src + 4);                              \
      }                                                                         \
    }                                                                           \
  }

#define STAGE_WRITE(R)                                                          \
  {                                                                             \
    _Pragma("unroll")                                                           \
    for (int u = 0; u < 3; ++u) {                                               \
      int c2 = tid + (R) * 1536 + u * 512;                                      \
      if (c2 < NCHUNK) {                                                        \
        int slot = c2 >> 4;                                                     \
        int d0 = (c2 & 15) * 8;                                                 \
        const float* f0 = (const float*)&va[2 * u];                             \
        bf16x8 o;                                                               \
        _Pragma("unroll")                                                       \
        for (int j = 0; j < 8; ++j) o[j] = (__bf16)f0[j];                       \
        *(bf16x8*)(lds + XS_OFF + slot * 256 + ((d0 * 2) ^ ((slot & 15) << 4))) = o; \
      }                                                                         \
    }                                                                           \
  }

// one L2 f-phase: load W2 frags for tap F, 8 kk x (4 reads + 4 MFMA)
#define L2PHASE(F)                                                              \
  {                                                                             \
    bf16x8 a2[8];                                                               \
    _Pragma("unroll")                                                           \
    for (int kk = 0; kk < 8; ++kk)                                              \
      a2[kk] = __builtin_bit_cast(bf16x8, *(const u16x8*)(w2fb + (F) * 16384 + kk * 2048)); \
    int sA = cbase + lrow + (F);       if (sA > 255) sA = 255;                  \
    int sB = cbase + 32 + lrow + (F);  if (sB > 255) sB = 255;                  \
    int sC = cbase + 64 + lrow + (F);  if (sC > 255) sC = 255;                  \
    int sD = cbase + 96 + lrow + (F);  if (sD > 255) sD = 255;                  \
    int bA = H1S_OFF + sA * 256, zA = (sA & 15) << 4;                           \
    int bB = H1S_OFF + sB * 256, zB = (sB & 15) << 4;                           \
    int bC = H1S_OFF + sC * 256, zC = (sC & 15) << 4;                           \
    int bD = H1S_OFF + sD * 256, zD = (sD & 15) << 4;                           \
    _Pragma("unroll")                                                           \
    for (int kk = 0; kk < 8; ++kk) {                                            \
      int ko = kk * 32 + hi16;                                                  \
      bf16x8 v0 = __builtin_bit_cast(bf16x8, *(const u16x8*)(lds + bA + (ko ^ zA))); \
      acc0 = __builtin_amdgcn_mfma_f32_32x32x16_bf16(a2[kk], v0, acc0, 0, 0, 0); \
      bf16x8 v1 = __builtin_bit_cast(bf16x8, *(const u16x8*)(lds + bB + (ko ^ zB))); \
      acc1 = __builtin_amdgcn_mfma_f32_32x32x16_bf16(a2[kk], v1, acc1, 0, 0, 0); \
      bf16x8 v2 = __builtin_bit_cast(bf16x8, *(const u16x8*)(lds + bC + (ko ^ zC))); \
      acc2 = __builtin_amdgcn_mfma_f32_32x32x16_bf16(a2[kk], v2, acc2, 0, 0, 0); \
      bf16x8 v3 = __builtin_bit_cast(bf16x8, *(const u16x8*)(lds + bD + (ko ^ zD))); \
      acc3 = __builtin_amdgcn_mfma_f32_32x32x16_bf16(a2[kk], v3, acc3, 0, 0, 0); \
    }                                                                           \
  }

__global__ __launch_bounds__(512) void cdssm_main(
    const float* __restrict__ q, const float* __restrict__ pos, const float* __restrict__ negs,
    const unsigned short* __restrict__ W1f, const unsigned short* __restrict__ W2f,
    const float* __restrict__ qb1, const float* __restrict__ db1,
    float* __restrict__ hpart) {
  extern __shared__ char lds[];
  const int tid = threadIdx.x;
  const int bid = blockIdx.x;
  const int seq = bid >> 1;
  const int half = bid & 1;
  const int branch = (seq < 64) ? 0 : 1;
  const float* xptr = (seq < 64) ? (q + (size_t)seq * 2048 * 128)
                    : (seq < 128) ? (pos + (size_t)(seq - 64) * 2048 * 128)
                                  : (negs + (size_t)(seq - 128) * 2048 * 128);
  const float* b1g = branch ? db1 : qb1;
  const int lo = half * 1022;
  const int hi = lo + 1022;   // 2*1022 = 2044 = T-4 outputs total

  if (tid < 128) ((float*)(lds + B1_OFF))[tid] = b1g[tid];

  const int lane = tid & 63;
  const int w = tid >> 6;            // 8 waves
  const int lrow = lane & 31;
  const int hi5 = lane >> 5;         // k-group
  const int r0 = (w & 3) * 32;       // output-row tile
  const int cbase = (w >> 2) * 128;  // 4 col tiles of 32
  const int row1 = r0 + lrow;
  const int hi16 = hi5 * 16;         // byte offset of k-group

  // fragment-major weight bases; +f*16384 +kk*2048 per use
  const unsigned short* w1fb = W1f + (size_t)branch * 49152 + row1 * 16 + hi5 * 8;
  const unsigned short* w2fb = W2f + (size_t)branch * 49152 + row1 * 16 + hi5 * 8;

  float vmax[16];
#pragma unroll
  for (int r = 0; r < 16; ++r) vmax[r] = -1e30f;

  // ---- prologue: stage X window 0 ----
  for (int c2 = tid; c2 < NCHUNK; c2 += 512) {
    int slot = c2 >> 4;
    int d0 = (c2 & 15) * 8;
    int t = lo + slot; if (t > 2047) t = 2047;
    const float* src = xptr + ((size_t)t * 128 + d0);
    float4 v0 = *(const float4*)src;
    float4 v1 = *(const float4*)(src + 4);
    bf16x8 o;
    o[0] = (__bf16)v0.x; o[1] = (__bf16)v0.y; o[2] = (__bf16)v0.z; o[3] = (__bf16)v0.w;
    o[4] = (__bf16)v1.x; o[5] = (__bf16)v1.y; o[6] = (__bf16)v1.z; o[7] = (__bf16)v1.w;
    *(bf16x8*)(lds + XS_OFF + slot * 256 + ((d0 * 2) ^ ((slot & 15) << 4))) = o;
  }
  __syncthreads();   // X(0) + bias ready

  for (int it = 0; it < NIT; ++it) {
    const int base = lo + it * STRIDE;

    f32x16 acc0, acc1, acc2, acc3;
#pragma unroll
    for (int r = 0; r < 16; ++r) { acc0[r] = 0.f; acc1[r] = 0.f; acc2[r] = 0.f; acc3[r] = 0.f; }

    // ---- layer 1: h1[k, s] = tanh(b1 + sum_f sum_d W1[k,d,f] * X[base+s+f, d]) ----
#pragma unroll 1
    for (int f = 0; f < 3; ++f) {
      bf16x8 a1[8];
#pragma unroll
      for (int kk = 0; kk < 8; ++kk)
        a1[kk] = __builtin_bit_cast(bf16x8, *(const u16x8*)(w1fb + f * 16384 + kk * 2048));
      int sA = cbase + lrow + f;        // max 128+96+31+2 = 257 = WIN-1, in range
      int sB = sA + 32;
      int sC = sA + 64;
      int sD = sA + 96;
      int bA = XS_OFF + sA * 256, zA = (sA & 15) << 4;
      int bB = XS_OFF + sB * 256, zB = (sB & 15) << 4;
      int bC = XS_OFF + sC * 256, zC = (sC & 15) << 4;
      int bD = XS_OFF + sD * 256, zD = (sD & 15) << 4;
#pragma unroll
      for (int kk = 0; kk < 8; ++kk) {
        int ko = kk * 32 + hi16;
        bf16x8 v0 = __builtin_bit_cast(bf16x8, *(const u16x8*)(lds + bA + (ko ^ zA)));
        acc0 = __builtin_amdgcn_mfma_f32_32x32x16_bf16(a1[kk], v0, acc0, 0, 0, 0);
        bf16x8 v1 = __builtin_bit_cast(bf16x8, *(const u16x8*)(lds + bB + (ko ^ zB)));
        acc1 = __builtin_amdgcn_mfma_f32_32x32x16_bf16(a1[kk], v1, acc1, 0, 0, 0);
        bf16x8 v2 = __builtin_bit_cast(bf16x8, *(const u16x8*)(lds + bC + (ko ^ zC)));
        acc2 = __builtin_amdgcn_mfma_f32_32x32x16_bf16(a1[kk], v2, acc2, 0, 0, 0);
        bf16x8 v3 = __builtin_bit_cast(bf16x8, *(const u16x8*)(lds + bD + (ko ^ zD)));
        acc3 = __builtin_amdgcn_mfma_f32_32x32x16_bf16(a1[kk], v3, acc3, 0, 0, 0);
      }
    }
    // epilogue: tanh + write h1 slots (cols 0..255 all valid)
#pragma unroll
    for (int tile = 0; tile < 4; ++tile) {
      const f32x16 acc = (tile == 0) ? acc0 : (tile == 1) ? acc1 : (tile == 2) ? acc2 : acc3;
      int s = cbase + tile * 32 + lrow;     // <= 255
      int wb = H1S_OFF + s * 256;
      int wz = (s & 15) << 4;
#pragma unroll
      for (int qd = 0; qd < 4; ++qd) {
        int k0 = r0 + qd * 8 + hi5 * 4;     // C rows: (reg&3)+8*(reg>>2)+4*hi
        float4 bq = *(const float4*)(lds + B1_OFF + k0 * 4);
        bf16x4 hv;
        hv[0] = (__bf16)fast_tanh(acc[qd * 4 + 0] + bq.x);
        hv[1] = (__bf16)fast_tanh(acc[qd * 4 + 1] + bq.y);
        hv[2] = (__bf16)fast_tanh(acc[qd * 4 + 2] + bq.z);
        hv[3] = (__bf16)fast_tanh(acc[qd * 4 + 3] + bq.w);
        *(bf16x4*)(lds + wb + ((k0 * 2) ^ wz)) = hv;
      }
    }
    __syncthreads();   // (1) h1 ready; all X(it) reads done

    // ---- layer 2 (3 f-phases) with T14 staging interleave ----
#pragma unroll
    for (int r = 0; r < 16; ++r) { acc0[r] = 0.f; acc1[r] = 0.f; acc2[r] = 0.f; acc3[r] = 0.f; }
    float4 va[6];
    const int basen = base + STRIDE;
    const bool st = (it < NIT - 1);

    if (st) STAGE_ISSUE(0);
    L2PHASE(0);
    if (st) { STAGE_WRITE(0); STAGE_ISSUE(1); }
    L2PHASE(1);
    if (st) { STAGE_WRITE(1); STAGE_ISSUE(2); }
    L2PHASE(2);
    if (st) STAGE_WRITE(2);

    // epilogue: running PRE-TANH max over valid outputs (tanh monotone; bias per-row -> k2)
#pragma unroll
    for (int tile = 0; tile < 4; ++tile) {
      const f32x16 acc = (tile == 0) ? acc0 : (tile == 1) ? acc1 : (tile == 2) ? acc2 : acc3;
      int s2 = cbase + tile * 32 + lrow;
      bool valid = (s2 < STRIDE) && (base + s2 < hi);
#pragma unroll
      for (int r = 0; r < 16; ++r) {
        float v = valid ? acc[r] : -1e30f;
        vmax[r] = fmaxf(vmax[r], v);
      }
    }
    __syncthreads();   // (2) X(it+1) ready; h1 free for overwrite
  }

  // reduce vmax across the 32 columns (each half-wave holds its own 16 rows)
#pragma unroll
  for (int r = 0; r < 16; ++r) {
    float v = vmax[r];
    v = fmaxf(v, __shfl_xor(v, 1, 64));
    v = fmaxf(v, __shfl_xor(v, 2, 64));
    v = fmaxf(v, __shfl_xor(v, 4, 64));
    v = fmaxf(v, __shfl_xor(v, 8, 64));
    v = fmaxf(v, __shfl_xor(v, 16, 64));
    vmax[r] = v;
  }
  float* hbuf = (float*)(lds + XS_OFF);   // reuse X region
  if (w < 4 && lrow == 0) {
#pragma unroll
    for (int r = 0; r < 16; ++r)
      hbuf[r0 + (r & 3) + 8 * (r >> 2) + 4 * hi5] = vmax[r];
  }
  __syncthreads();
  if (w >= 4 && lrow == 0) {
#pragma unroll
    for (int r = 0; r < 16; ++r) {
      int row = r0 + (r & 3) + 8 * (r >> 2) + 4 * hi5;
      hbuf[row] = fmaxf(hbuf[row], vmax[r]);
    }
  }
  __syncthreads();
  if (tid < 128) hpart[(size_t)bid * 128 + tid] = hbuf[tid];   // raw (pre-tanh) max
}

// ---------------- k2: combine halves, bias+tanh, project, tanh ----------------
__global__ void k2_proj(const float* __restrict__ hpart,
                        const float* __restrict__ qsw, const float* __restrict__ qsb,
                        const float* __restrict__ dsw, const float* __restrict__ dsb,
                        const float* __restrict__ qb2, const float* __restrict__ db2,
                        float* __restrict__ s_out) {
  int seq = blockIdx.x;        // 256
  int l = threadIdx.x;         // 64
  const float* sw = (seq < 64) ? qsw : dsw;
  const float* sb = (seq < 64) ? qsb : dsb;
  const float* b2 = (seq < 64) ? qb2 : db2;
  const float* h0 = hpart + (size_t)(2 * seq) * 128;
  const float* h1 = h0 + 128;
  float acc = sb[l];
  for (int k = 0; k < 128; ++k)
    acc += fast_tanh(fmaxf(h0[k], h1[k]) + b2[k]) * sw[l * 128 + k];
  s_out[(size_t)seq * 64 + l] = fast_tanh(acc);
}

// ---------------- k3: dots, gamma, softmax ----------------
__global__ void k3_softmax(const float* __restrict__ s_out,
                           const float* __restrict__ gw, const float* __restrict__ gb,
                           float* __restrict__ out) {
  int b = threadIdx.x;   // 64
  const float* qs = s_out + (size_t)b * 64;
  const float* ps = s_out + (size_t)(64 + b) * 64;
  const float* n0 = s_out + (size_t)(128 + b) * 64;
  const float* n1 = s_out + (size_t)(192 + b) * 64;
  float d0 = 0.f, d1 = 0.f, d2 = 0.f;
  for (int l = 0; l < 64; ++l) {
    float v = qs[l];
    d0 += v * ps[l];
    d1 += v * n0[l];
    d2 += v * n1[l];
  }
  float g = gw[0], bb = gb[0];
  d0 = g * d0 + bb; d1 = g * d1 + bb; d2 = g * d2 + bb;
  float m = fmaxf(d0, fmaxf(d1, d2));
  float e0 = expf(d0 - m), e1 = expf(d1 - m), e2 = expf(d2 - m);
  float inv = 1.0f / (e0 + e1 + e2);
  out[b * 3 + 0] = e0 * inv;
  out[b * 3 + 1] = e1 * inv;
  out[b * 3 + 2] = e2 * inv;
}

extern "C" void kernel_launch(void* const* d_in, const int* in_sizes, int n_in,
                              void* d_out, int out_size, void* d_ws, size_t ws_size,
                              hipStream_t stream) {
  const float* q    = (const float*)d_in[0];
  const float* pos  = (const float*)d_in[1];
  const float* negs = (const float*)d_in[2];
  const float* qw1  = (const float*)d_in[3];
  const float* qb1  = (const float*)d_in[4];
  const float* qw2  = (const float*)d_in[5];
  const float* qb2  = (const float*)d_in[6];
  const float* qsw  = (const float*)d_in[7];
  const float* qsb  = (const float*)d_in[8];
  const float* dw1  = (const float*)d_in[9];
  const float* db1  = (const float*)d_in[10];
  const float* dw2  = (const float*)d_in[11];
  const float* db2  = (const float*)d_in[12];
  const float* dsw  = (const float*)d_in[13];
  const float* dsb  = (const float*)d_in[14];
  const float* gw   = (const float*)d_in[15];
  const float* gb   = (const float*)d_in[16];
  float* out = (float*)d_out;

  char* ws = (char*)d_ws;
  unsigned short* W1f = (unsigned short*)(ws);             // 98304 elems = 196608 B
  unsigned short* W2f = (unsigned short*)(ws + 196608);    // 98304 elems = 196608 B
  float* hpart        = (float*)(ws + 393216);             // 512*128*4 = 262144 B
  float* s_out        = (float*)(ws + 655360);             // 256*64*4  = 65536 B

  hipFuncSetAttribute((const void*)cdssm_main,
                      hipFuncAttributeMaxDynamicSharedMemorySize, LDS_TOTAL);

  prep_kernel<<<768, 256, 0, stream>>>(qw1, qw2, dw1, dw2, W1f, W2f);
  cdssm_main<<<512, 512, LDS_TOTAL, stream>>>(q, pos, negs, W1f, W2f, qb1, db1, hpart);
  k2_proj<<<256, 64, 0, stream>>>(hpart, qsw, qsb, dsw, dsb, qb2, db2, s_out);
  k3_softmax<<<1, 64, 0, stream>>>(s_out, gw, gb, out);
}

// Round 8
// 214.482 us; speedup vs baseline: 1.9593x; 1.9593x over previous
//
#include <hip/hip_runtime.h>
#include <stdint.h>

// CDSSM: conv1(128ch,k3) -> tanh -> conv2(128ch,k3) -> tanh -> max_t -> proj -> tanh
//        then dots(q·pos, q·negs) -> gamma -> softmax.  B=64,T=2048,D=K=K2=128,L=64,J=2.
// R8: LDS-traffic attack. R4 is LDS-read-bound (96 b128/wave/iter, 4x redundant:
//     4 k-waves read identical B-frags). Re-split waves 2 kgroups x 4 colgroups:
//     B-frag shared across the wave's 2 k-tiles -> 48 reads/wave/iter (2x cut).
//     W frag loads double but are L2-resident (VMEM pipe, overlaps LDS pipe).
//     acc stays 2 tiles (32 regs, R4-proven envelope), staging va[8] (32 regs).
//     Pre-tanh running max (R7-verified) removes L2-epilogue tanh.

typedef __bf16 bf16x8 __attribute__((ext_vector_type(8)));
typedef __bf16 bf16x4 __attribute__((ext_vector_type(4)));
typedef float f32x16 __attribute__((ext_vector_type(16)));
typedef unsigned short u16x8 __attribute__((ext_vector_type(8)));

__device__ __forceinline__ unsigned short f2bf(float f) {
  unsigned u = __builtin_bit_cast(unsigned, f);
  u = u + 0x7FFFu + ((u >> 16) & 1u);   // RTNE
  return (unsigned short)(u >> 16);
}

__device__ __forceinline__ float fast_tanh(float x) {
  x = fminf(10.0f, fmaxf(-10.0f, x));
  float t = __builtin_amdgcn_exp2f(x * -2.8853900817779268f);   // e^{-2x}
  return (1.0f - t) * __builtin_amdgcn_rcpf(1.0f + t);
}

// ---------------- prep: fp32 [k][d][f] -> bf16 fragment-major [br][f][kk][row][hi][j] ----------------
__global__ void prep_kernel(const float* __restrict__ qw1, const float* __restrict__ qw2,
                            const float* __restrict__ dw1, const float* __restrict__ dw2,
                            unsigned short* __restrict__ W1f, unsigned short* __restrict__ W2f) {
  int gid = blockIdx.x * 256 + threadIdx.x;          // 768*256 = 196608 exact
  int which = gid >= 98304;                          // 0: W1f, 1: W2f
  int e = which ? gid - 98304 : gid;
  int br = e / 49152; int r = e % 49152;
  int f = r / 16384; int r2 = r & 16383;
  int kk = r2 >> 11; int row = (r2 >> 4) & 127; int hi = (r2 >> 3) & 1; int j = r2 & 7;
  int c = kk * 16 + hi * 8 + j;
  const float* src = which ? (br ? dw2 : qw2) : (br ? dw1 : qw1);
  (which ? W2f : W1f)[e] = f2bf(src[row * 384 + c * 3 + f]);
}

// ---------------- main fused conv kernel ----------------
// LDS (dynamic, 65536 B):
//  XS  0     : bf16 [128 slot][128 d], swizzled  (32768)
//  H1S 32768 : bf16 [126 slot][128 k], swizzled  (32256)
//  B1  65024 : float[128] bias1                  (512)
#define XS_OFF  0
#define H1S_OFF 32768
#define B1_OFF  65024
#define LDS_TOTAL 65536
#define WIN 128        // X slots per window (4*512 staging chunks exactly)
#define STRIDE 124     // fresh L2 outputs per iter (126 h1 slots - 2)
#define NIT 9          // 124*8 = 992, last iter covers remaining 30

__global__ __launch_bounds__(512) void cdssm_main(
    const float* __restrict__ q, const float* __restrict__ pos, const float* __restrict__ negs,
    const unsigned short* __restrict__ W1f, const unsigned short* __restrict__ W2f,
    const float* __restrict__ qb1, const float* __restrict__ db1,
    float* __restrict__ hpart) {
  extern __shared__ char lds[];
  const int tid = threadIdx.x;
  const int bid = blockIdx.x;
  const int seq = bid >> 1;
  const int half = bid & 1;
  const int branch = (seq < 64) ? 0 : 1;
  const float* xptr = (seq < 64) ? (q + (size_t)seq * 2048 * 128)
                    : (seq < 128) ? (pos + (size_t)(seq - 64) * 2048 * 128)
                                  : (negs + (size_t)(seq - 128) * 2048 * 128);
  const float* b1g = branch ? db1 : qb1;
  const int lo = half * 1022;
  const int hi = lo + 1022;   // 2*1022 = 2044 = T-4 outputs total

  if (tid < 128) ((float*)(lds + B1_OFF))[tid] = b1g[tid];

  const int lane = tid & 63;
  const int w = tid >> 6;            // 8 waves
  const int lrow = lane & 31;
  const int hi5 = lane >> 5;         // k-group within reduction
  const int kg = w & 1;              // k-row group: rows [kg*64, kg*64+64)
  const int cg = w >> 1;             // col group: cols [cg*32, cg*32+32)
  const int hi16 = hi5 * 16;         // byte offset of reduction k-slice
  const int scol = cg * 32 + lrow;   // this lane's output column (h1/L2 slot)

  // fragment-major weight bases; frag addr = base + f*16384 + kk*2048 (+512 for 2nd k-tile)
  const unsigned short* w1fb = W1f + (size_t)branch * 49152 + (kg * 64 + lrow) * 16 + hi5 * 8;
  const unsigned short* w2fb = W2f + (size_t)branch * 49152 + (kg * 64 + lrow) * 16 + hi5 * 8;

  float vmaxA[16], vmaxB[16];
#pragma unroll
  for (int r = 0; r < 16; ++r) { vmaxA[r] = -1e30f; vmaxB[r] = -1e30f; }

  // ---- prologue: stage X window 0 (2048 chunks = 4 rounds) ----
#pragma unroll
  for (int u = 0; u < 4; ++u) {
    int c2 = tid + 512 * u;
    int slot = c2 >> 4;
    int d0 = (c2 & 15) * 8;
    int t = lo + slot; if (t > 2047) t = 2047;
    const float* src = xptr + ((size_t)t * 128 + d0);
    float4 v0 = *(const float4*)src;
    float4 v1 = *(const float4*)(src + 4);
    bf16x8 o;
    o[0] = (__bf16)v0.x; o[1] = (__bf16)v0.y; o[2] = (__bf16)v0.z; o[3] = (__bf16)v0.w;
    o[4] = (__bf16)v1.x; o[5] = (__bf16)v1.y; o[6] = (__bf16)v1.z; o[7] = (__bf16)v1.w;
    *(bf16x8*)(lds + XS_OFF + slot * 256 + ((d0 * 2) ^ ((slot & 15) << 4))) = o;
  }
  __syncthreads();   // X(0) + bias ready

  for (int it = 0; it < NIT; ++it) {
    const int base = lo + it * STRIDE;

    // ---- layer 1: h1[k, s] = tanh(b1 + sum_f sum_d W1[k,d,f] * X[base+s+f, d]) ----
    {
      f32x16 acc0, acc1;
#pragma unroll
      for (int r = 0; r < 16; ++r) { acc0[r] = 0.f; acc1[r] = 0.f; }
#pragma unroll 1
      for (int f = 0; f < 3; ++f) {
        int sv = scol + f; if (sv > WIN - 1) sv = WIN - 1;   // clamped -> discarded outputs
        int bb = XS_OFF + sv * 256, bz = (sv & 15) << 4;
#pragma unroll
        for (int kk = 0; kk < 8; ++kk) {
          bf16x8 a0 = __builtin_bit_cast(bf16x8,
              *(const u16x8*)(w1fb + f * 16384 + kk * 2048));
          bf16x8 a1 = __builtin_bit_cast(bf16x8,
              *(const u16x8*)(w1fb + f * 16384 + kk * 2048 + 512));
          bf16x8 bv = __builtin_bit_cast(bf16x8,
              *(const u16x8*)(lds + bb + ((kk * 32 + hi16) ^ bz)));
          acc0 = __builtin_amdgcn_mfma_f32_32x32x16_bf16(a0, bv, acc0, 0, 0, 0);
          acc1 = __builtin_amdgcn_mfma_f32_32x32x16_bf16(a1, bv, acc1, 0, 0, 0);
        }
      }
      // epilogue: tanh + write h1 slot scol (if valid); rows kg*64 + tile*32 + pat
      if (scol < 126) {
        int wb = H1S_OFF + scol * 256;
        int wz = (scol & 15) << 4;
#pragma unroll
        for (int tile = 0; tile < 2; ++tile) {
          const f32x16 acc = tile ? acc1 : acc0;
#pragma unroll
          for (int qd = 0; qd < 4; ++qd) {
            int k0 = kg * 64 + tile * 32 + qd * 8 + hi5 * 4;  // C rows: (reg&3)+8*(reg>>2)+4*hi
            float4 bq = *(const float4*)(lds + B1_OFF + k0 * 4);
            bf16x4 hv;
            hv[0] = (__bf16)fast_tanh(acc[qd * 4 + 0] + bq.x);
            hv[1] = (__bf16)fast_tanh(acc[qd * 4 + 1] + bq.y);
            hv[2] = (__bf16)fast_tanh(acc[qd * 4 + 2] + bq.z);
            hv[3] = (__bf16)fast_tanh(acc[qd * 4 + 3] + bq.w);
            *(bf16x4*)(lds + wb + ((k0 * 2) ^ wz)) = hv;
          }
        }
      }
    }
    __syncthreads();   // (1) h1 ready; all X(it) reads done

    // ---- issue next-window global loads (latency hides under L2 MFMA) ----
    float4 va[8];
    if (it < NIT - 1) {
      const int basen = base + STRIDE;
#pragma unroll
      for (int u = 0; u < 4; ++u) {
        int c2 = tid + 512 * u;
        int slot = c2 >> 4;
        int d0 = (c2 & 15) * 8;
        int t = basen + slot; if (t > 2047) t = 2047;
        const float* src = xptr + ((size_t)t * 128 + d0);
        va[2 * u]     = *(const float4*)src;
        va[2 * u + 1] = *(const float4*)(src + 4);
      }
    }

    // ---- layer 2: y2[k2, s2] = b2 + sum_f sum_c W2[k2,c,f] * h1[c, s2+f] (pre-tanh max) ----
    {
      f32x16 acc0, acc1;
#pragma unroll
      for (int r = 0; r < 16; ++r) { acc0[r] = 0.f; acc1[r] = 0.f; }
#pragma unroll 1
      for (int f = 0; f < 3; ++f) {
        int sv = scol + f; if (sv > 125) sv = 125;
        int bb = H1S_OFF + sv * 256, bz = (sv & 15) << 4;
#pragma unroll
        for (int kk = 0; kk < 8; ++kk) {
          bf16x8 a0 = __builtin_bit_cast(bf16x8,
              *(const u16x8*)(w2fb + f * 16384 + kk * 2048));
          bf16x8 a1 = __builtin_bit_cast(bf16x8,
              *(const u16x8*)(w2fb + f * 16384 + kk * 2048 + 512));
          bf16x8 bv = __builtin_bit_cast(bf16x8,
              *(const u16x8*)(lds + bb + ((kk * 32 + hi16) ^ bz)));
          acc0 = __builtin_amdgcn_mfma_f32_32x32x16_bf16(a0, bv, acc0, 0, 0, 0);
          acc1 = __builtin_amdgcn_mfma_f32_32x32x16_bf16(a1, bv, acc1, 0, 0, 0);
        }
      }

      // ---- convert + write next X window (X reads finished at barrier(1)) ----
      if (it < NIT - 1) {
#pragma unroll
        for (int u = 0; u < 4; ++u) {
          int c2 = tid + 512 * u;
          int slot = c2 >> 4;
          int d0 = (c2 & 15) * 8;
          const float* f0 = (const float*)&va[2 * u];
          bf16x8 o;
#pragma unroll
          for (int j = 0; j < 8; ++j) o[j] = (__bf16)f0[j];
          *(bf16x8*)(lds + XS_OFF + slot * 256 + ((d0 * 2) ^ ((slot & 15) << 4))) = o;
        }
      }

      // epilogue: running PRE-TANH max over valid outputs (tanh monotone; bias per-row -> k2)
      {
        bool valid = (scol < STRIDE) && (base + scol < hi);
#pragma unroll
        for (int r = 0; r < 16; ++r) {
          float v0 = valid ? acc0[r] : -1e30f;
          float v1 = valid ? acc1[r] : -1e30f;
          vmaxA[r] = fmaxf(vmaxA[r], v0);
          vmaxB[r] = fmaxf(vmaxB[r], v1);
        }
      }
    }
    __syncthreads();   // (2) X(it+1) ready; h1 free for overwrite
  }

  // reduce vmax across the 32 columns of this wave
#pragma unroll
  for (int r = 0; r < 16; ++r) {
    float a = vmaxA[r], b = vmaxB[r];
    a = fmaxf(a, __shfl_xor(a, 1, 64));  b = fmaxf(b, __shfl_xor(b, 1, 64));
    a = fmaxf(a, __shfl_xor(a, 2, 64));  b = fmaxf(b, __shfl_xor(b, 2, 64));
    a = fmaxf(a, __shfl_xor(a, 4, 64));  b = fmaxf(b, __shfl_xor(b, 4, 64));
    a = fmaxf(a, __shfl_xor(a, 8, 64));  b = fmaxf(b, __shfl_xor(b, 8, 64));
    a = fmaxf(a, __shfl_xor(a, 16, 64)); b = fmaxf(b, __shfl_xor(b, 16, 64));
    vmaxA[r] = a; vmaxB[r] = b;
  }
  __syncthreads();   // all L2 h1-reads done; reuse XS region
  float* hbuf = (float*)(lds + XS_OFF);   // [4 cg][128 rows]
  if (lrow == 0) {
#pragma unroll
    for (int r = 0; r < 16; ++r) {
      int rl = (r & 3) + 8 * (r >> 2) + 4 * hi5;
      hbuf[cg * 128 + kg * 64 + rl]      = vmaxA[r];
      hbuf[cg * 128 + kg * 64 + 32 + rl] = vmaxB[r];
    }
  }
  __syncthreads();
  if (tid < 128) {
    float m = fmaxf(fmaxf(hbuf[tid], hbuf[128 + tid]),
                    fmaxf(hbuf[256 + tid], hbuf[384 + tid]));
    hpart[(size_t)bid * 128 + tid] = m;   // raw (pre-tanh, pre-bias) max
  }
}

// ---------------- k2: combine halves, bias+tanh, project, tanh ----------------
__global__ void k2_proj(const float* __restrict__ hpart,
                        const float* __restrict__ qsw, const float* __restrict__ qsb,
                        const float* __restrict__ dsw, const float* __restrict__ dsb,
                        const float* __restrict__ qb2, const float* __restrict__ db2,
                        float* __restrict__ s_out) {
  int seq = blockIdx.x;        // 256
  int l = threadIdx.x;         // 64
  const float* sw = (seq < 64) ? qsw : dsw;
  const float* sb = (seq < 64) ? qsb : dsb;
  const float* b2 = (seq < 64) ? qb2 : db2;
  const float* h0 = hpart + (size_t)(2 * seq) * 128;
  const float* h1 = h0 + 128;
  float acc = sb[l];
  for (int k = 0; k < 128; ++k)
    acc += fast_tanh(fmaxf(h0[k], h1[k]) + b2[k]) * sw[l * 128 + k];
  s_out[(size_t)seq * 64 + l] = fast_tanh(acc);
}

// ---------------- k3: dots, gamma, softmax ----------------
__global__ void k3_softmax(const float* __restrict__ s_out,
                           const float* __restrict__ gw, const float* __restrict__ gb,
                           float* __restrict__ out) {
  int b = threadIdx.x;   // 64
  const float* qs = s_out + (size_t)b * 64;
  const float* ps = s_out + (size_t)(64 + b) * 64;
  const float* n0 = s_out + (size_t)(128 + b) * 64;
  const float* n1 = s_out + (size_t)(192 + b) * 64;
  float d0 = 0.f, d1 = 0.f, d2 = 0.f;
  for (int l = 0; l < 64; ++l) {
    float v = qs[l];
    d0 += v * ps[l];
    d1 += v * n0[l];
    d2 += v * n1[l];
  }
  float g = gw[0], bb = gb[0];
  d0 = g * d0 + bb; d1 = g * d1 + bb; d2 = g * d2 + bb;
  float m = fmaxf(d0, fmaxf(d1, d2));
  float e0 = expf(d0 - m), e1 = expf(d1 - m), e2 = expf(d2 - m);
  float inv = 1.0f / (e0 + e1 + e2);
  out[b * 3 + 0] = e0 * inv;
  out[b * 3 + 1] = e1 * inv;
  out[b * 3 + 2] = e2 * inv;
}

extern "C" void kernel_launch(void* const* d_in, const int* in_sizes, int n_in,
                              void* d_out, int out_size, void* d_ws, size_t ws_size,
                              hipStream_t stream) {
  const float* q    = (const float*)d_in[0];
  const float* pos  = (const float*)d_in[1];
  const float* negs = (const float*)d_in[2];
  const float* qw1  = (const float*)d_in[3];
  const float* qb1  = (const float*)d_in[4];
  const float* qw2  = (const float*)d_in[5];
  const float* qb2  = (const float*)d_in[6];
  const float* qsw  = (const float*)d_in[7];
  const float* qsb  = (const float*)d_in[8];
  const float* dw1  = (const float*)d_in[9];
  const float* db1  = (const float*)d_in[10];
  const float* dw2  = (const float*)d_in[11];
  const float* db2  = (const float*)d_in[12];
  const float* dsw  = (const float*)d_in[13];
  const float* dsb  = (const float*)d_in[14];
  const float* gw   = (const float*)d_in[15];
  const float* gb   = (const float*)d_in[16];
  float* out = (float*)d_out;

  char* ws = (char*)d_ws;
  unsigned short* W1f = (unsigned short*)(ws);             // 98304 elems = 196608 B
  unsigned short* W2f = (unsigned short*)(ws + 196608);    // 98304 elems = 196608 B
  float* hpart        = (float*)(ws + 393216);             // 512*128*4 = 262144 B
  float* s_out        = (float*)(ws + 655360);             // 256*64*4  = 65536 B

  hipFuncSetAttribute((const void*)cdssm_main,
                      hipFuncAttributeMaxDynamicSharedMemorySize, LDS_TOTAL);

  prep_kernel<<<768, 256, 0, stream>>>(qw1, qw2, dw1, dw2, W1f, W2f);
  cdssm_main<<<512, 512, LDS_TOTAL, stream>>>(q, pos, negs, W1f, W2f, qb1, db1, hpart);
  k2_proj<<<256, 64, 0, stream>>>(hpart, qsw, qsb, dsw, dsb, qb2, db2, s_out);
  k3_softmax<<<1, 64, 0, stream>>>(s_out, gw, gb, out);
}

// Round 9
// 179.852 us; speedup vs baseline: 2.3366x; 1.1925x over previous
//
#include <hip/hip_runtime.h>
#include <stdint.h>

// CDSSM: conv1(128ch,k3) -> tanh -> conv2(128ch,k3) -> tanh -> max_t -> proj -> tanh
//        then dots(q·pos, q·negs) -> gamma -> softmax.  B=64,T=2048,D=K=K2=128,L=64,J=2.
// R9: wave-specialized pipeline. 4 conv1-waves + 4 conv2-waves per block, each owning
//     one 32-row k-tile with taps 0,1 PINNED in 64 VGPRs (loaded once) + tap2 transient.
//     Small double-buffered windows (X 32 slots, h1 32 slots -> 33 KB LDS, 2 blocks/CU).
//     One barrier/iter: L1(win i) || L2(win i-1) || stage X(win i+1) (1 chunk/thread).
//     Pre-tanh running max (R7/R8-proven); bias2+tanh in k2.

typedef __bf16 bf16x8 __attribute__((ext_vector_type(8)));
typedef __bf16 bf16x4 __attribute__((ext_vector_type(4)));
typedef float f32x16 __attribute__((ext_vector_type(16)));
typedef unsigned short u16x8 __attribute__((ext_vector_type(8)));

__device__ __forceinline__ unsigned short f2bf(float f) {
  unsigned u = __builtin_bit_cast(unsigned, f);
  u = u + 0x7FFFu + ((u >> 16) & 1u);   // RTNE
  return (unsigned short)(u >> 16);
}

__device__ __forceinline__ float fast_tanh(float x) {
  x = fminf(10.0f, fmaxf(-10.0f, x));
  float t = __builtin_amdgcn_exp2f(x * -2.8853900817779268f);   // e^{-2x}
  return (1.0f - t) * __builtin_amdgcn_rcpf(1.0f + t);
}

// ---------------- prep: fp32 [k][d][f] -> bf16 fragment-major [br][f][kk][row][hi][j] ----------------
__global__ void prep_kernel(const float* __restrict__ qw1, const float* __restrict__ qw2,
                            const float* __restrict__ dw1, const float* __restrict__ dw2,
                            unsigned short* __restrict__ W1f, unsigned short* __restrict__ W2f) {
  int gid = blockIdx.x * 256 + threadIdx.x;          // 768*256 = 196608 exact
  int which = gid >= 98304;                          // 0: W1f, 1: W2f
  int e = which ? gid - 98304 : gid;
  int br = e / 49152; int r = e % 49152;
  int f = r / 16384; int r2 = r & 16383;
  int kk = r2 >> 11; int row = (r2 >> 4) & 127; int hi = (r2 >> 3) & 1; int j = r2 & 7;
  int c = kk * 16 + hi * 8 + j;
  const float* src = which ? (br ? dw2 : qw2) : (br ? dw1 : qw1);
  (which ? W2f : W1f)[e] = f2bf(src[row * 384 + c * 3 + f]);
}

// ---------------- main fused conv kernel ----------------
// LDS (dynamic, 33280 B -> 2 blocks/CU):
//  XS0  0     : bf16 [2 buf][32 slot][128 d], swizzled  (16384)
//  H1S0 16384 : bf16 [2 buf][32 slot][128 k], swizzled  (16384)
//  B1   32768 : float[128] bias1                        (512)
#define XS0   0
#define H1S0  16384
#define B1_OFF 32768
#define LDS_TOTAL 33280
#define YS 28          // fresh conv2 outputs per window
#define NWIN 37        // ceil(1022/28)

__global__ __launch_bounds__(512) void cdssm_main(
    const float* __restrict__ q, const float* __restrict__ pos, const float* __restrict__ negs,
    const unsigned short* __restrict__ W1f, const unsigned short* __restrict__ W2f,
    const float* __restrict__ qb1, const float* __restrict__ db1,
    float* __restrict__ hpart) {
  extern __shared__ char lds[];
  const int tid = threadIdx.x;
  const int bid = blockIdx.x;
  const int seq = bid >> 1;
  const int half = bid & 1;
  const int branch = (seq < 64) ? 0 : 1;
  const float* xptr = (seq < 64) ? (q + (size_t)seq * 2048 * 128)
                    : (seq < 128) ? (pos + (size_t)(seq - 64) * 2048 * 128)
                                  : (negs + (size_t)(seq - 128) * 2048 * 128);
  const float* b1g = branch ? db1 : qb1;
  const int lo = half * 1022;
  const int hi = lo + 1022;   // 2*1022 = 2044 = T-4 outputs total

  if (tid < 128) ((float*)(lds + B1_OFF))[tid] = b1g[tid];

  const int lane = tid & 63;
  const int w = tid >> 6;            // 8 waves
  const int lrow = lane & 31;
  const int hi5 = lane >> 5;
  const int role = w >> 2;           // 0 = conv1 waves, 1 = conv2 waves
  const int kt = w & 3;              // k-tile: output rows [kt*32, kt*32+32)
  const int hi16 = hi5 * 16;

  // fragment-major base for THIS wave's k-tile; frag = wfb + f*16384 + kk*2048
  const unsigned short* wfb = (role ? W2f : W1f) + (size_t)branch * 49152
                              + (kt * 32 + lrow) * 16 + hi5 * 8;

  // pin taps 0,1 (64 VGPRs); tap 2 loaded transient per use
  bf16x8 ap[16];
#pragma unroll
  for (int f = 0; f < 2; ++f)
#pragma unroll
    for (int kk = 0; kk < 8; ++kk)
      ap[f * 8 + kk] = __builtin_bit_cast(bf16x8,
          *(const u16x8*)(wfb + f * 16384 + kk * 2048));

  float vmax[16];
#pragma unroll
  for (int r = 0; r < 16; ++r) vmax[r] = -1e30f;

  // staging geometry: 512 chunks (32 slots x 16), exactly 1 per thread
  const int slot_s = tid >> 4;
  const int d0_s = (tid & 15) * 8;

  // ---- prologue: stage X window 0 into Xbuf0 ----
  {
    int t = lo + slot_s; if (t > 2047) t = 2047;
    const float* src = xptr + ((size_t)t * 128 + d0_s);
    float4 v0 = *(const float4*)src;
    float4 v1 = *(const float4*)(src + 4);
    bf16x8 o;
    o[0] = (__bf16)v0.x; o[1] = (__bf16)v0.y; o[2] = (__bf16)v0.z; o[3] = (__bf16)v0.w;
    o[4] = (__bf16)v1.x; o[5] = (__bf16)v1.y; o[6] = (__bf16)v1.z; o[7] = (__bf16)v1.w;
    *(bf16x8*)(lds + XS0 + slot_s * 256 + ((d0_s * 2) ^ ((slot_s & 15) << 4))) = o;
  }
  __syncthreads();   // X(0) + bias + pinned weights ready

  for (int i = 0; i <= NWIN; ++i) {
    // ---- issue staging loads for window i+1 (hide HBM under compute) ----
    float4 va0, va1;
    const bool doStage = (i < NWIN - 1);
    if (doStage) {
      int t = lo + (i + 1) * YS + slot_s; if (t > 2047) t = 2047;
      const float* src = xptr + ((size_t)t * 128 + d0_s);
      va0 = *(const float4*)src;
      va1 = *(const float4*)(src + 4);
    }

    if (role == 0) {
      // ---- conv1 wave: compute h1 window i into h1buf[i&1] ----
      if (i < NWIN) {
        const int xb = XS0 + (i & 1) * 8192;
        f32x16 acc;
#pragma unroll
        for (int r = 0; r < 16; ++r) acc[r] = 0.f;
#pragma unroll
        for (int f = 0; f < 2; ++f) {
          int sv = lrow + f; if (sv > 31) sv = 31;   // cols 30,31 garbage -> unwritten
          int bb = xb + sv * 256, bz = (sv & 15) << 4;
#pragma unroll
          for (int kk = 0; kk < 8; ++kk) {
            bf16x8 bv = __builtin_bit_cast(bf16x8,
                *(const u16x8*)(lds + bb + ((kk * 32 + hi16) ^ bz)));
            acc = __builtin_amdgcn_mfma_f32_32x32x16_bf16(ap[f * 8 + kk], bv, acc, 0, 0, 0);
          }
        }
        {   // tap 2 transient
          int sv = lrow + 2; if (sv > 31) sv = 31;
          int bb = xb + sv * 256, bz = (sv & 15) << 4;
#pragma unroll
          for (int kk = 0; kk < 8; ++kk) {
            bf16x8 av = __builtin_bit_cast(bf16x8,
                *(const u16x8*)(wfb + 2 * 16384 + kk * 2048));
            bf16x8 bv = __builtin_bit_cast(bf16x8,
                *(const u16x8*)(lds + bb + ((kk * 32 + hi16) ^ bz)));
            acc = __builtin_amdgcn_mfma_f32_32x32x16_bf16(av, bv, acc, 0, 0, 0);
          }
        }
        // epilogue: bias1 + tanh -> h1 (cols 0..29 valid)
        if (lrow < 30) {
          int wb2 = H1S0 + (i & 1) * 8192 + lrow * 256;
          int wz = (lrow & 15) << 4;
#pragma unroll
          for (int qd = 0; qd < 4; ++qd) {
            int k0 = kt * 32 + qd * 8 + hi5 * 4;   // C rows: (reg&3)+8*(reg>>2)+4*hi
            float4 bq = *(const float4*)(lds + B1_OFF + k0 * 4);
            bf16x4 hv;
            hv[0] = (__bf16)fast_tanh(acc[qd * 4 + 0] + bq.x);
            hv[1] = (__bf16)fast_tanh(acc[qd * 4 + 1] + bq.y);
            hv[2] = (__bf16)fast_tanh(acc[qd * 4 + 2] + bq.z);
            hv[3] = (__bf16)fast_tanh(acc[qd * 4 + 3] + bq.w);
            *(bf16x4*)(lds + wb2 + ((k0 * 2) ^ wz)) = hv;
          }
        }
      }
    } else {
      // ---- conv2 wave: consume h1 window i-1 from h1buf[(i&1)^1] ----
      if (i >= 1) {
        const int hb = H1S0 + ((i & 1) ^ 1) * 8192;
        f32x16 acc;
#pragma unroll
        for (int r = 0; r < 16; ++r) acc[r] = 0.f;
#pragma unroll
        for (int f = 0; f < 2; ++f) {
          int sv = lrow + f; if (sv > 31) sv = 31;
          int bb = hb + sv * 256, bz = (sv & 15) << 4;
#pragma unroll
          for (int kk = 0; kk < 8; ++kk) {
            bf16x8 bv = __builtin_bit_cast(bf16x8,
                *(const u16x8*)(lds + bb + ((kk * 32 + hi16) ^ bz)));
            acc = __builtin_amdgcn_mfma_f32_32x32x16_bf16(ap[f * 8 + kk], bv, acc, 0, 0, 0);
          }
        }
        {   // tap 2 transient
          int sv = lrow + 2; if (sv > 31) sv = 31;
          int bb = hb + sv * 256, bz = (sv & 15) << 4;
#pragma unroll
          for (int kk = 0; kk < 8; ++kk) {
            bf16x8 av = __builtin_bit_cast(bf16x8,
                *(const u16x8*)(wfb + 2 * 16384 + kk * 2048));
            bf16x8 bv = __builtin_bit_cast(bf16x8,
                *(const u16x8*)(lds + bb + ((kk * 32 + hi16) ^ bz)));
            acc = __builtin_amdgcn_mfma_f32_32x32x16_bf16(av, bv, acc, 0, 0, 0);
          }
        }
        // epilogue: running PRE-TANH max (bias2+tanh deferred to k2)
        const int basep = lo + (i - 1) * YS;
        const bool valid = (lrow < YS) && (basep + lrow < hi);
#pragma unroll
        for (int r = 0; r < 16; ++r)
          vmax[r] = fmaxf(vmax[r], valid ? acc[r] : -1e30f);
      }
    }

    // ---- convert + write staged X window i+1 into Xbuf[(i+1)&1] ----
    if (doStage) {
      bf16x8 o;
      o[0] = (__bf16)va0.x; o[1] = (__bf16)va0.y; o[2] = (__bf16)va0.z; o[3] = (__bf16)va0.w;
      o[4] = (__bf16)va1.x; o[5] = (__bf16)va1.y; o[6] = (__bf16)va1.z; o[7] = (__bf16)va1.w;
      *(bf16x8*)(lds + XS0 + ((i + 1) & 1) * 8192 + slot_s * 256 +
                 ((d0_s * 2) ^ ((slot_s & 15) << 4))) = o;
    }
    __syncthreads();
  }

  // ---- final: conv2 waves reduce vmax across their 32 columns, write hpart ----
  if (role == 1) {
#pragma unroll
    for (int r = 0; r < 16; ++r) {
      float v = vmax[r];
      v = fmaxf(v, __shfl_xor(v, 1, 64));
      v = fmaxf(v, __shfl_xor(v, 2, 64));
      v = fmaxf(v, __shfl_xor(v, 4, 64));
      v = fmaxf(v, __shfl_xor(v, 8, 64));
      v = fmaxf(v, __shfl_xor(v, 16, 64));
      vmax[r] = v;
    }
  }
  float* hbuf = (float*)(lds + XS0);   // X buffers dead now
  if (role == 1 && lrow == 0) {
#pragma unroll
    for (int r = 0; r < 16; ++r) {
      int rl = (r & 3) + 8 * (r >> 2) + 4 * hi5;
      hbuf[kt * 32 + rl] = vmax[r];
    }
  }
  __syncthreads();
  if (tid < 128) hpart[(size_t)bid * 128 + tid] = hbuf[tid];   // raw pre-tanh, pre-bias max
}

// ---------------- k2: combine halves, bias+tanh, project, tanh ----------------
__global__ void k2_proj(const float* __restrict__ hpart,
                        const float* __restrict__ qsw, const float* __restrict__ qsb,
                        const float* __restrict__ dsw, const float* __restrict__ dsb,
                        const float* __restrict__ qb2, const float* __restrict__ db2,
                        float* __restrict__ s_out) {
  int seq = blockIdx.x;        // 256
  int l = threadIdx.x;         // 64
  const float* sw = (seq < 64) ? qsw : dsw;
  const float* sb = (seq < 64) ? qsb : dsb;
  const float* b2 = (seq < 64) ? qb2 : db2;
  const float* h0 = hpart + (size_t)(2 * seq) * 128;
  const float* h1 = h0 + 128;
  float acc = sb[l];
  for (int k = 0; k < 128; ++k)
    acc += fast_tanh(fmaxf(h0[k], h1[k]) + b2[k]) * sw[l * 128 + k];
  s_out[(size_t)seq * 64 + l] = fast_tanh(acc);
}

// ---------------- k3: dots, gamma, softmax ----------------
__global__ void k3_softmax(const float* __restrict__ s_out,
                           const float* __restrict__ gw, const float* __restrict__ gb,
                           float* __restrict__ out) {
  int b = threadIdx.x;   // 64
  const float* qs = s_out + (size_t)b * 64;
  const float* ps = s_out + (size_t)(64 + b) * 64;
  const float* n0 = s_out + (size_t)(128 + b) * 64;
  const float* n1 = s_out + (size_t)(192 + b) * 64;
  float d0 = 0.f, d1 = 0.f, d2 = 0.f;
  for (int l = 0; l < 64; ++l) {
    float v = qs[l];
    d0 += v * ps[l];
    d1 += v * n0[l];
    d2 += v * n1[l];
  }
  float g = gw[0], bb = gb[0];
  d0 = g * d0 + bb; d1 = g * d1 + bb; d2 = g * d2 + bb;
  float m = fmaxf(d0, fmaxf(d1, d2));
  float e0 = expf(d0 - m), e1 = expf(d1 - m), e2 = expf(d2 - m);
  float inv = 1.0f / (e0 + e1 + e2);
  out[b * 3 + 0] = e0 * inv;
  out[b * 3 + 1] = e1 * inv;
  out[b * 3 + 2] = e2 * inv;
}

extern "C" void kernel_launch(void* const* d_in, const int* in_sizes, int n_in,
                              void* d_out, int out_size, void* d_ws, size_t ws_size,
                              hipStream_t stream) {
  const float* q    = (const float*)d_in[0];
  const float* pos  = (const float*)d_in[1];
  const float* negs = (const float*)d_in[2];
  const float* qw1  = (const float*)d_in[3];
  const float* qb1  = (const float*)d_in[4];
  const float* qw2  = (const float*)d_in[5];
  const float* qb2  = (const float*)d_in[6];
  const float* qsw  = (const float*)d_in[7];
  const float* qsb  = (const float*)d_in[8];
  const float* dw1  = (const float*)d_in[9];
  const float* db1  = (const float*)d_in[10];
  const float* dw2  = (const float*)d_in[11];
  const float* db2  = (const float*)d_in[12];
  const float* dsw  = (const float*)d_in[13];
  const float* dsb  = (const float*)d_in[14];
  const float* gw   = (const float*)d_in[15];
  const float* gb   = (const float*)d_in[16];
  float* out = (float*)d_out;

  char* ws = (char*)d_ws;
  unsigned short* W1f = (unsigned short*)(ws);             // 98304 elems = 196608 B
  unsigned short* W2f = (unsigned short*)(ws + 196608);    // 98304 elems = 196608 B
  float* hpart        = (float*)(ws + 393216);             // 512*128*4 = 262144 B
  float* s_out        = (float*)(ws + 655360);             // 256*64*4  = 65536 B

  hipFuncSetAttribute((const void*)cdssm_main,
                      hipFuncAttributeMaxDynamicSharedMemorySize, LDS_TOTAL);

  prep_kernel<<<768, 256, 0, stream>>>(qw1, qw2, dw1, dw2, W1f, W2f);
  cdssm_main<<<512, 512, LDS_TOTAL, stream>>>(q, pos, negs, W1f, W2f, qb1, db1, hpart);
  k2_proj<<<256, 64, 0, stream>>>(hpart, qsw, qsb, dsw, dsb, qb2, db2, s_out);
  k3_softmax<<<1, 64, 0, stream>>>(s_out, gw, gb, out);
}

// Round 10
// 158.597 us; speedup vs baseline: 2.6497x; 1.1340x over previous
//
#include <hip/hip_runtime.h>
#include <stdint.h>

// CDSSM: conv1(128ch,k3) -> tanh -> conv2(128ch,k3) -> tanh -> max_t -> proj -> tanh
//        then dots(q·pos, q·negs) -> gamma -> softmax.  B=64,T=2048,D=K=K2=128,L=64,J=2.
// R10: R9 wave-specialized skeleton (4 conv1 + 4 conv2 waves, taps 0,1 pinned in 64
//      VGPR, tap2 transient, pre-tanh max, 1 barrier/iter) but 64-slot windows and
//      2 column-panels per wave sharing the A-fragments: A-cost per output halves,
//      NWIN 37->18, barriers 38->19. vmax[16] folds both panels (time-max is over
//      all columns anyway).

typedef __bf16 bf16x8 __attribute__((ext_vector_type(8)));
typedef __bf16 bf16x4 __attribute__((ext_vector_type(4)));
typedef float f32x16 __attribute__((ext_vector_type(16)));
typedef unsigned short u16x8 __attribute__((ext_vector_type(8)));

__device__ __forceinline__ unsigned short f2bf(float f) {
  unsigned u = __builtin_bit_cast(unsigned, f);
  u = u + 0x7FFFu + ((u >> 16) & 1u);   // RTNE
  return (unsigned short)(u >> 16);
}

__device__ __forceinline__ float fast_tanh(float x) {
  x = fminf(10.0f, fmaxf(-10.0f, x));
  float t = __builtin_amdgcn_exp2f(x * -2.8853900817779268f);   // e^{-2x}
  return (1.0f - t) * __builtin_amdgcn_rcpf(1.0f + t);
}

// ---------------- prep: fp32 [k][d][f] -> bf16 fragment-major [br][f][kk][row][hi][j] ----------------
__global__ void prep_kernel(const float* __restrict__ qw1, const float* __restrict__ qw2,
                            const float* __restrict__ dw1, const float* __restrict__ dw2,
                            unsigned short* __restrict__ W1f, unsigned short* __restrict__ W2f) {
  int gid = blockIdx.x * 256 + threadIdx.x;          // 768*256 = 196608 exact
  int which = gid >= 98304;                          // 0: W1f, 1: W2f
  int e = which ? gid - 98304 : gid;
  int br = e / 49152; int r = e % 49152;
  int f = r / 16384; int r2 = r & 16383;
  int kk = r2 >> 11; int row = (r2 >> 4) & 127; int hi = (r2 >> 3) & 1; int j = r2 & 7;
  int c = kk * 16 + hi * 8 + j;
  const float* src = which ? (br ? dw2 : qw2) : (br ? dw1 : qw1);
  (which ? W2f : W1f)[e] = f2bf(src[row * 384 + c * 3 + f]);
}

// ---------------- main fused conv kernel ----------------
// LDS (dynamic, 65024 B):
//  XS0  0     : bf16 [2 buf][64 slot][128 d], swizzled  (32768)
//  H1S0 32768 : bf16 [2 buf][62 slot][128 k], swizzled  (31744)
//  B1   64512 : float[128] bias1                        (512)
#define XS0    0
#define H1S0   32768
#define B1_OFF 64512
#define LDS_TOTAL 65024
#define YS 60          // fresh conv2 outputs per window
#define NWIN 18        // ceil(1022/60)

__global__ __launch_bounds__(512) void cdssm_main(
    const float* __restrict__ q, const float* __restrict__ pos, const float* __restrict__ negs,
    const unsigned short* __restrict__ W1f, const unsigned short* __restrict__ W2f,
    const float* __restrict__ qb1, const float* __restrict__ db1,
    float* __restrict__ hpart) {
  extern __shared__ char lds[];
  const int tid = threadIdx.x;
  const int bid = blockIdx.x;
  const int seq = bid >> 1;
  const int half = bid & 1;
  const int branch = (seq < 64) ? 0 : 1;
  const float* xptr = (seq < 64) ? (q + (size_t)seq * 2048 * 128)
                    : (seq < 128) ? (pos + (size_t)(seq - 64) * 2048 * 128)
                                  : (negs + (size_t)(seq - 128) * 2048 * 128);
  const float* b1g = branch ? db1 : qb1;
  const int lo = half * 1022;
  const int hi = lo + 1022;   // 2*1022 = 2044 = T-4 outputs total

  if (tid < 128) ((float*)(lds + B1_OFF))[tid] = b1g[tid];

  const int lane = tid & 63;
  const int w = tid >> 6;            // 8 waves
  const int lrow = lane & 31;
  const int hi5 = lane >> 5;
  const int role = w >> 2;           // 0 = conv1 waves, 1 = conv2 waves
  const int kt = w & 3;              // k-tile: output rows [kt*32, kt*32+32)
  const int hi16 = hi5 * 16;

  // fragment-major base for THIS wave's k-tile; frag = wfb + f*16384 + kk*2048
  const unsigned short* wfb = (role ? W2f : W1f) + (size_t)branch * 49152
                              + (kt * 32 + lrow) * 16 + hi5 * 8;

  // pin taps 0,1 (64 VGPRs); tap 2 loaded transient per use
  bf16x8 ap[16];
#pragma unroll
  for (int f = 0; f < 2; ++f)
#pragma unroll
    for (int kk = 0; kk < 8; ++kk)
      ap[f * 8 + kk] = __builtin_bit_cast(bf16x8,
          *(const u16x8*)(wfb + f * 16384 + kk * 2048));

  float vmax[16];
#pragma unroll
  for (int r = 0; r < 16; ++r) vmax[r] = -1e30f;

  // staging geometry: 1024 chunks (64 slots x 16), 2 per thread (slot_s, slot_s+32)
  const int slot_s = tid >> 4;
  const int d0_s = (tid & 15) * 8;

  // ---- prologue: stage X window 0 into Xbuf0 ----
#pragma unroll
  for (int u = 0; u < 2; ++u) {
    int sl = slot_s + u * 32;
    int t = lo + sl; if (t > 2047) t = 2047;
    const float* src = xptr + ((size_t)t * 128 + d0_s);
    float4 v0 = *(const float4*)src;
    float4 v1 = *(const float4*)(src + 4);
    bf16x8 o;
    o[0] = (__bf16)v0.x; o[1] = (__bf16)v0.y; o[2] = (__bf16)v0.z; o[3] = (__bf16)v0.w;
    o[4] = (__bf16)v1.x; o[5] = (__bf16)v1.y; o[6] = (__bf16)v1.z; o[7] = (__bf16)v1.w;
    *(bf16x8*)(lds + XS0 + sl * 256 + ((d0_s * 2) ^ ((sl & 15) << 4))) = o;
  }
  __syncthreads();   // X(0) + bias + pinned weights ready

  for (int i = 0; i <= NWIN; ++i) {
    // ---- issue staging loads for window i+1 (hide HBM under compute) ----
    float4 va[4];
    const bool doStage = (i < NWIN - 1);
    if (doStage) {
      const int tb = lo + (i + 1) * YS;
#pragma unroll
      for (int u = 0; u < 2; ++u) {
        int t = tb + slot_s + u * 32; if (t > 2047) t = 2047;
        const float* src = xptr + ((size_t)t * 128 + d0_s);
        va[2 * u]     = *(const float4*)src;
        va[2 * u + 1] = *(const float4*)(src + 4);
      }
    }

    if (role == 0) {
      // ---- conv1 wave: compute h1 window i (2 panels) into h1buf[i&1] ----
      if (i < NWIN) {
        const int xb = XS0 + (i & 1) * 16384;
        f32x16 acc0, acc1;
#pragma unroll
        for (int r = 0; r < 16; ++r) { acc0[r] = 0.f; acc1[r] = 0.f; }
#pragma unroll
        for (int f = 0; f < 2; ++f) {
          int sv0 = lrow + f;                              // <= 33, no clamp
          int sv1 = 32 + lrow + f; if (sv1 > 63) sv1 = 63; // cols 62,63 garbage
          int b0 = xb + sv0 * 256, z0 = (sv0 & 15) << 4;
          int b1 = xb + sv1 * 256, z1 = (sv1 & 15) << 4;
#pragma unroll
          for (int kk = 0; kk < 8; ++kk) {
            int ko = kk * 32 + hi16;
            bf16x8 bv0 = __builtin_bit_cast(bf16x8,
                *(const u16x8*)(lds + b0 + (ko ^ z0)));
            acc0 = __builtin_amdgcn_mfma_f32_32x32x16_bf16(ap[f * 8 + kk], bv0, acc0, 0, 0, 0);
            bf16x8 bv1 = __builtin_bit_cast(bf16x8,
                *(const u16x8*)(lds + b1 + (ko ^ z1)));
            acc1 = __builtin_amdgcn_mfma_f32_32x32x16_bf16(ap[f * 8 + kk], bv1, acc1, 0, 0, 0);
          }
        }
        {   // tap 2 transient (shared across both panels)
          int sv0 = lrow + 2;
          int sv1 = 32 + lrow + 2; if (sv1 > 63) sv1 = 63;
          int b0 = xb + sv0 * 256, z0 = (sv0 & 15) << 4;
          int b1 = xb + sv1 * 256, z1 = (sv1 & 15) << 4;
#pragma unroll
          for (int kk = 0; kk < 8; ++kk) {
            bf16x8 av = __builtin_bit_cast(bf16x8,
                *(const u16x8*)(wfb + 2 * 16384 + kk * 2048));
            int ko = kk * 32 + hi16;
            bf16x8 bv0 = __builtin_bit_cast(bf16x8,
                *(const u16x8*)(lds + b0 + (ko ^ z0)));
            acc0 = __builtin_amdgcn_mfma_f32_32x32x16_bf16(av, bv0, acc0, 0, 0, 0);
            bf16x8 bv1 = __builtin_bit_cast(bf16x8,
                *(const u16x8*)(lds + b1 + (ko ^ z1)));
            acc1 = __builtin_amdgcn_mfma_f32_32x32x16_bf16(av, bv1, acc1, 0, 0, 0);
          }
        }
        // epilogue: bias1 + tanh -> h1 (cols 0..61 valid)
        const int hb = H1S0 + (i & 1) * 15872;
#pragma unroll
        for (int p = 0; p < 2; ++p) {
          const f32x16 acc = p ? acc1 : acc0;
          int s = p * 32 + lrow;
          if (s < 62) {
            int wb2 = hb + s * 256;
            int wz = (s & 15) << 4;
#pragma unroll
            for (int qd = 0; qd < 4; ++qd) {
              int k0 = kt * 32 + qd * 8 + hi5 * 4;   // C rows: (reg&3)+8*(reg>>2)+4*hi
              float4 bq = *(const float4*)(lds + B1_OFF + k0 * 4);
              bf16x4 hv;
              hv[0] = (__bf16)fast_tanh(acc[qd * 4 + 0] + bq.x);
              hv[1] = (__bf16)fast_tanh(acc[qd * 4 + 1] + bq.y);
              hv[2] = (__bf16)fast_tanh(acc[qd * 4 + 2] + bq.z);
              hv[3] = (__bf16)fast_tanh(acc[qd * 4 + 3] + bq.w);
              *(bf16x4*)(lds + wb2 + ((k0 * 2) ^ wz)) = hv;
            }
          }
        }
      }
    } else {
      // ---- conv2 wave: consume h1 window i-1 (2 panels) from h1buf[(i&1)^1] ----
      if (i >= 1) {
        const int hb = H1S0 + ((i & 1) ^ 1) * 15872;
        f32x16 acc0, acc1;
#pragma unroll
        for (int r = 0; r < 16; ++r) { acc0[r] = 0.f; acc1[r] = 0.f; }
#pragma unroll
        for (int f = 0; f < 2; ++f) {
          int sv0 = lrow + f;                              // <= 33
          int sv1 = 32 + lrow + f; if (sv1 > 61) sv1 = 61;
          int b0 = hb + sv0 * 256, z0 = (sv0 & 15) << 4;
          int b1 = hb + sv1 * 256, z1 = (sv1 & 15) << 4;
#pragma unroll
          for (int kk = 0; kk < 8; ++kk) {
            int ko = kk * 32 + hi16;
            bf16x8 bv0 = __builtin_bit_cast(bf16x8,
                *(const u16x8*)(lds + b0 + (ko ^ z0)));
            acc0 = __builtin_amdgcn_mfma_f32_32x32x16_bf16(ap[f * 8 + kk], bv0, acc0, 0, 0, 0);
            bf16x8 bv1 = __builtin_bit_cast(bf16x8,
                *(const u16x8*)(lds + b1 + (ko ^ z1)));
            acc1 = __builtin_amdgcn_mfma_f32_32x32x16_bf16(ap[f * 8 + kk], bv1, acc1, 0, 0, 0);
          }
        }
        {   // tap 2 transient
          int sv0 = lrow + 2;
          int sv1 = 32 + lrow + 2; if (sv1 > 61) sv1 = 61;
          int b0 = hb + sv0 * 256, z0 = (sv0 & 15) << 4;
          int b1 = hb + sv1 * 256, z1 = (sv1 & 15) << 4;
#pragma unroll
          for (int kk = 0; kk < 8; ++kk) {
            bf16x8 av = __builtin_bit_cast(bf16x8,
                *(const u16x8*)(wfb + 2 * 16384 + kk * 2048));
            int ko = kk * 32 + hi16;
            bf16x8 bv0 = __builtin_bit_cast(bf16x8,
                *(const u16x8*)(lds + b0 + (ko ^ z0)));
            acc0 = __builtin_amdgcn_mfma_f32_32x32x16_bf16(av, bv0, acc0, 0, 0, 0);
            bf16x8 bv1 = __builtin_bit_cast(bf16x8,
                *(const u16x8*)(lds + b1 + (ko ^ z1)));
            acc1 = __builtin_amdgcn_mfma_f32_32x32x16_bf16(av, bv1, acc1, 0, 0, 0);
          }
        }
        // epilogue: running PRE-TANH max, both panels fold into vmax[16]
        const int base = lo + (i - 1) * YS;
        const bool valid0 = (base + lrow < hi);                       // lrow < 60 always
        const int s2b = 32 + lrow;
        const bool valid1 = (s2b < YS) && (base + s2b < hi);
#pragma unroll
        for (int r = 0; r < 16; ++r) {
          float v0 = valid0 ? acc0[r] : -1e30f;
          float v1 = valid1 ? acc1[r] : -1e30f;
          vmax[r] = fmaxf(vmax[r], fmaxf(v0, v1));
        }
      }
    }

    // ---- convert + write staged X window i+1 into Xbuf[(i+1)&1] ----
    if (doStage) {
      const int xbn = XS0 + ((i + 1) & 1) * 16384;
#pragma unroll
      for (int u = 0; u < 2; ++u) {
        int sl = slot_s + u * 32;
        const float* f0 = (const float*)&va[2 * u];
        bf16x8 o;
#pragma unroll
        for (int j = 0; j < 8; ++j) o[j] = (__bf16)f0[j];
        *(bf16x8*)(lds + xbn + sl * 256 + ((d0_s * 2) ^ ((sl & 15) << 4))) = o;
      }
    }
    __syncthreads();
  }

  // ---- final: conv2 waves reduce vmax across their 32 columns, write hpart ----
  if (role == 1) {
#pragma unroll
    for (int r = 0; r < 16; ++r) {
      float v = vmax[r];
      v = fmaxf(v, __shfl_xor(v, 1, 64));
      v = fmaxf(v, __shfl_xor(v, 2, 64));
      v = fmaxf(v, __shfl_xor(v, 4, 64));
      v = fmaxf(v, __shfl_xor(v, 8, 64));
      v = fmaxf(v, __shfl_xor(v, 16, 64));
      vmax[r] = v;
    }
  }
  float* hbuf = (float*)(lds + XS0);   // X buffers dead now
  if (role == 1 && lrow == 0) {
#pragma unroll
    for (int r = 0; r < 16; ++r) {
      int rl = (r & 3) + 8 * (r >> 2) + 4 * hi5;
      hbuf[kt * 32 + rl] = vmax[r];
    }
  }
  __syncthreads();
  if (tid < 128) hpart[(size_t)bid * 128 + tid] = hbuf[tid];   // raw pre-tanh, pre-bias max
}

// ---------------- k2: combine halves, bias+tanh, project, tanh ----------------
__global__ void k2_proj(const float* __restrict__ hpart,
                        const float* __restrict__ qsw, const float* __restrict__ qsb,
                        const float* __restrict__ dsw, const float* __restrict__ dsb,
                        const float* __restrict__ qb2, const float* __restrict__ db2,
                        float* __restrict__ s_out) {
  int seq = blockIdx.x;        // 256
  int l = threadIdx.x;         // 64
  const float* sw = (seq < 64) ? qsw : dsw;
  const float* sb = (seq < 64) ? qsb : dsb;
  const float* b2 = (seq < 64) ? qb2 : db2;
  const float* h0 = hpart + (size_t)(2 * seq) * 128;
  const float* h1 = h0 + 128;
  float acc = sb[l];
  for (int k = 0; k < 128; ++k)
    acc += fast_tanh(fmaxf(h0[k], h1[k]) + b2[k]) * sw[l * 128 + k];
  s_out[(size_t)seq * 64 + l] = fast_tanh(acc);
}

// ---------------- k3: dots, gamma, softmax ----------------
__global__ void k3_softmax(const float* __restrict__ s_out,
                           const float* __restrict__ gw, const float* __restrict__ gb,
                           float* __restrict__ out) {
  int b = threadIdx.x;   // 64
  const float* qs = s_out + (size_t)b * 64;
  const float* ps = s_out + (size_t)(64 + b) * 64;
  const float* n0 = s_out + (size_t)(128 + b) * 64;
  const float* n1 = s_out + (size_t)(192 + b) * 64;
  float d0 = 0.f, d1 = 0.f, d2 = 0.f;
  for (int l = 0; l < 64; ++l) {
    float v = qs[l];
    d0 += v * ps[l];
    d1 += v * n0[l];
    d2 += v * n1[l];
  }
  float g = gw[0], bb = gb[0];
  d0 = g * d0 + bb; d1 = g * d1 + bb; d2 = g * d2 + bb;
  float m = fmaxf(d0, fmaxf(d1, d2));
  float e0 = expf(d0 - m), e1 = expf(d1 - m), e2 = expf(d2 - m);
  float inv = 1.0f / (e0 + e1 + e2);
  out[b * 3 + 0] = e0 * inv;
  out[b * 3 + 1] = e1 * inv;
  out[b * 3 + 2] = e2 * inv;
}

extern "C" void kernel_launch(void* const* d_in, const int* in_sizes, int n_in,
                              void* d_out, int out_size, void* d_ws, size_t ws_size,
                              hipStream_t stream) {
  const float* q    = (const float*)d_in[0];
  const float* pos  = (const float*)d_in[1];
  const float* negs = (const float*)d_in[2];
  const float* qw1  = (const float*)d_in[3];
  const float* qb1  = (const float*)d_in[4];
  const float* qw2  = (const float*)d_in[5];
  const float* qb2  = (const float*)d_in[6];
  const float* qsw  = (const float*)d_in[7];
  const float* qsb  = (const float*)d_in[8];
  const float* dw1  = (const float*)d_in[9];
  const float* db1  = (const float*)d_in[10];
  const float* dw2  = (const float*)d_in[11];
  const float* db2  = (const float*)d_in[12];
  const float* dsw  = (const float*)d_in[13];
  const float* dsb  = (const float*)d_in[14];
  const float* gw   = (const float*)d_in[15];
  const float* gb   = (const float*)d_in[16];
  float* out = (float*)d_out;

  char* ws = (char*)d_ws;
  unsigned short* W1f = (unsigned short*)(ws);             // 98304 elems = 196608 B
  unsigned short* W2f = (unsigned short*)(ws + 196608);    // 98304 elems = 196608 B
  float* hpart        = (float*)(ws + 393216);             // 512*128*4 = 262144 B
  float* s_out        = (float*)(ws + 655360);             // 256*64*4  = 65536 B

  hipFuncSetAttribute((const void*)cdssm_main,
                      hipFuncAttributeMaxDynamicSharedMemorySize, LDS_TOTAL);

  prep_kernel<<<768, 256, 0, stream>>>(qw1, qw2, dw1, dw2, W1f, W2f);
  cdssm_main<<<512, 512, LDS_TOTAL, stream>>>(q, pos, negs, W1f, W2f, qb1, db1, hpart);
  k2_proj<<<256, 64, 0, stream>>>(hpart, qsw, qsb, dsw, dsb, qb2, db2, s_out);
  k3_softmax<<<1, 64, 0, stream>>>(s_out, gw, gb, out);
}